// Round 13
// baseline (101.975 us; speedup 1.0000x reference)
//
#include <hip/hip_runtime.h>
#include <hip/hip_bf16.h>

#define B_    8
#define Q_    64
#define C_    512
#define HW_   256
#define E_    512
#define HATT_ 128
#define HMLP_ 512
#define NCLS_ 14
#define NLAB_ 64

typedef unsigned short u16;
typedef unsigned int   u32;
typedef __attribute__((ext_vector_type(8))) short short8;   // 8 bf16
typedef __attribute__((ext_vector_type(4))) float f32x4;

// ws layout (bytes) — total 12,468,224 < 12,582,912 (proven available R2):
//   GBp   @ 0       : 256x1024 f32 (l,cq)-partials of [gamma|beta]  1 MB
//                     (aliased by pPb [512u][2nh][512c] bf16 after prep)
//   pA    @ 1048576 : 512x2 f32 attn-mass partials (per unique)      4 KB
//   sperm @ 1052672 : 512 int  bq sorted by key=(b*64+l)             2 KB
//   uled  @ 1054720 : 512 int  per-unique: rep bq | (l<<16)          2 KB
//   ustart@ 1056768 : 513 int  run starts into sperm                 4 KB
//   nuniq @ 1060864 : 1 int                                          4 KB
//   Dlp   @ 1064960 : 256x128 f32 (l,cq)-partials of beta@W_att_h  128 KB
//   Gl    @ 1196032 : 64x512 f32 gamma per label                   128 KB
//   Bl    @ 1327104 : 64x512 f32 beta per label                    128 KB
//   W1bf  @ 1458176 : 512x512 bf16 W_mlp1                          512 KB
//   fT    @ 1982464 : 8x256x512 bf16 feature^T [b][n][c]             2 MB
//   WgT   @ 4079616 : 64 x [16ss][128h][4slot] bf16x8 gamma-scaled,  8 MB
//                     pre-swizzled (slot = g' ^ ((h>>1)&3)) so linear
//                     DMA into LDS yields the conflict-free tile.

__device__ __forceinline__ float gelu_fast(float x) {
    const float ax = fabsf(x);
    const float t  = __builtin_amdgcn_rcpf(1.0f + 0.3275911f * ax);
    const float p  = t * (0.254829592f +
                     t * (-0.284496736f +
                     t * (1.421413741f +
                     t * (-1.453152027f +
                     t * 1.061405429f))));
    const float e  = __expf(-x * x);
    const float er = copysignf(1.0f - p * e, x);
    return 0.5f * x * (1.0f + er);
}
__device__ __forceinline__ float sigmoid_(float x) {
    return 1.0f / (1.0f + __expf(-x));
}
__device__ __forceinline__ u16 f2bf(float x) {              // RNE f32->bf16
    u32 u = __float_as_uint(x);
    u32 r = (u + 0x7fffu + ((u >> 16) & 1u)) >> 16;
    return (u16)r;
}
__device__ __forceinline__ float bf2f(u16 u) {
    return __uint_as_float(((u32)u) << 16);
}
// async global->LDS DMA, 16B/lane; LDS dest = wave-uniform base + lane*16
__device__ __forceinline__ void gl2lds16(const void* gsrc, void* ldsdst) {
    __builtin_amdgcn_global_load_lds(
        (const __attribute__((address_space(1))) u32*)gsrc,
        (__attribute__((address_space(3))) u32*)ldsdst, 16, 0, 0);
}

// ---------------------------------------------------------------------------
// K1 prep_gbp: 256 blocks (l,cq) x 256 thr.  GBp partials of qt @ W_film.
// ---------------------------------------------------------------------------
__global__ __launch_bounds__(256) void prep_gbp(
    const float* __restrict__ qt, const float* __restrict__ W_film,
    float* __restrict__ GBp) {
    __shared__ float qrow[128];
    const int bid = blockIdx.x, t = threadIdx.x;
    const int l = bid >> 2, cq = bid & 3;
    if (t < 128) qrow[t] = qt[l * E_ + cq * 128 + t];
    __syncthreads();
    const float* wp = W_film + (size_t)(cq * 128) * 1024 + t * 4;
    f32x4 a = {0.f, 0.f, 0.f, 0.f};
    #pragma unroll 8
    for (int c = 0; c < 128; ++c) {
        const float4 w = *(const float4*)(wp + (size_t)c * 1024);
        const float q = qrow[c];
        a.x += q * w.x; a.y += q * w.y; a.z += q * w.z; a.w += q * w.w;
    }
    *(f32x4*)&GBp[(size_t)bid * 1024 + t * 4] = a;
}

// ---------------------------------------------------------------------------
// K2 prep_rest: 577 blocks x 256 thr.
//  [0,256)   fT[b][n][c] = bf16(feature[b][c][n])
//  [256,320) W1bf = bf16(W_mlp1)
//  320       sort by key=(b*64+l) + unique-run detection (dedup tables)
//  [321,577) (l,cq): Gl/Bl (inline GBp reduce); WgT pre-scaled+pre-swizzled;
//            Dlp partials (non-atomic)
// ---------------------------------------------------------------------------
__global__ __launch_bounds__(256) void prep_rest(
    const float* __restrict__ feature, const float* __restrict__ W_mlp1,
    const int* __restrict__ label_ids, const float* __restrict__ b_film,
    const float* __restrict__ W_att_h, const float* __restrict__ GBp,
    u16* __restrict__ W1bf, u16* __restrict__ fT,
    int* __restrict__ sperm, int* __restrict__ uled,
    int* __restrict__ ustart, int* __restrict__ nuniq,
    float* __restrict__ Gl, float* __restrict__ Bl,
    u16* __restrict__ WgT, float* __restrict__ Dlp) {

    __shared__ __align__(16) char sm[16896];
    const int bid = blockIdx.x, t = threadIdx.x;

    if (bid < 256) {                       // ---- fT transpose
        float (*tile)[65] = (float(*)[65])sm;
        const int b = bid >> 5, c0 = ((bid >> 2) & 7) * 64, n0 = (bid & 3) * 64;
        const float* fb = feature + (size_t)b * C_ * HW_;
        const int cl = t >> 2, nq = t & 3;
        #pragma unroll
        for (int i = 0; i < 4; ++i) {
            float4 v = *(const float4*)&fb[(c0 + cl) * HW_ + n0 + nq * 16 + i * 4];
            tile[cl][nq * 16 + i * 4 + 0] = v.x;
            tile[cl][nq * 16 + i * 4 + 1] = v.y;
            tile[cl][nq * 16 + i * 4 + 2] = v.z;
            tile[cl][nq * 16 + i * 4 + 3] = v.w;
        }
        __syncthreads();
        const int nl = t >> 2, cqq = t & 3;
        u16 pk[16];
        #pragma unroll
        for (int k = 0; k < 16; ++k) pk[k] = f2bf(tile[cqq * 16 + k][nl]);
        u16* dst = fT + (size_t)(b * HW_ + n0 + nl) * C_ + c0 + cqq * 16;
        *(uint4*)dst       = *(uint4*)pk;
        *(uint4*)(dst + 8) = *(uint4*)(pk + 8);
    } else if (bid < 320) {                // ---- W1 -> bf16
        const int b2 = bid - 256;
        #pragma unroll
        for (int k = 0; k < 2; ++k) {
            const int idx = (b2 * 512 + k * 256 + t) * 8;
            float4 v0 = *(const float4*)&W_mlp1[idx];
            float4 v1 = *(const float4*)&W_mlp1[idx + 4];
            u16 pk[8] = {f2bf(v0.x), f2bf(v0.y), f2bf(v0.z), f2bf(v0.w),
                         f2bf(v1.x), f2bf(v1.y), f2bf(v1.z), f2bf(v1.w)};
            *(uint4*)&W1bf[idx] = *(uint4*)pk;
        }
    } else if (bid == 320) {               // ---- sort + unique runs
        int* cnt  = (int*)sm;              // 512
        int* skey = cnt + 512;             // 512
        int* sbq  = skey + 512;            // 512  (6 KB total)
        cnt[t] = 0; cnt[t + 256] = 0;
        __syncthreads();
        const int bqa = t, bqb = t + 256;
        const int ka = (bqa >> 6) * 64 + label_ids[bqa];
        const int kb = (bqb >> 6) * 64 + label_ids[bqb];
        atomicAdd(&cnt[ka], 1);
        atomicAdd(&cnt[kb], 1);
        __syncthreads();
        if (t == 0) {
            int run = 0;
            for (int i = 0; i < 512; ++i) { const int c = cnt[i]; cnt[i] = run; run += c; }
        }
        __syncthreads();
        const int pa = atomicAdd(&cnt[ka], 1); skey[pa] = ka; sbq[pa] = bqa;
        const int pb = atomicAdd(&cnt[kb], 1); skey[pb] = kb; sbq[pb] = bqb;
        __syncthreads();
        sperm[t] = sbq[t]; sperm[t + 256] = sbq[t + 256];
        if (t == 0) {
            int u = -1;
            for (int i = 0; i < 512; ++i) {
                if (i == 0 || skey[i] != skey[i - 1]) {
                    ++u;
                    ustart[u] = i;
                    uled[u] = sbq[i] | ((skey[i] & 63) << 16);
                }
            }
            nuniq[0] = u + 1;
            for (int j = u + 1; j <= 512; ++j) ustart[j] = 512;
        }
    } else {                               // ---- Gl/Bl + WgT + Dlp
        float* g_s  = (float*)sm;          // 128
        float* b_s  = g_s + 128;           // 128
        float* dred = b_s + 128;           // 256
        const int wb = bid - 321;
        const int l = wb >> 2, cq = wb & 3;

        if (t < 128) {
            const int c = cq * 128 + t;
            float g = b_film[c], be = b_film[512 + c];
            #pragma unroll
            for (int j = 0; j < 4; ++j) {
                g  += GBp[(size_t)(l * 4 + j) * 1024 + c];
                be += GBp[(size_t)(l * 4 + j) * 1024 + 512 + c];
            }
            g_s[t] = g; b_s[t] = be;
            Gl[l * C_ + c] = g;
            Bl[l * C_ + c] = be;
        }
        __syncthreads();

        const int h = t & 127, ch = t >> 7;
        const int hswz = (h >> 1) & 3;
        float dl = 0.f;
        #pragma unroll
        for (int sl = 0; sl < 2; ++sl) {
            const int ss = cq * 4 + ch * 2 + sl;    // superstep in [0,16)
            char* dst = (char*)WgT + (size_t)l * 131072 + ss * 8192 + h * 64;
            #pragma unroll
            for (int g = 0; g < 4; ++g) {
                u16 pk[8];
                #pragma unroll
                for (int j = 0; j < 8; ++j) {
                    const int cl = ch * 64 + sl * 32 + g * 8 + j;
                    const float w = W_att_h[(size_t)(cq * 128 + cl) * HATT_ + h];
                    pk[j] = f2bf(g_s[cl] * w);
                    dl += b_s[cl] * w;
                }
                *(uint4*)(dst + ((g ^ hswz) * 16)) = *(uint4*)pk;
            }
        }
        dred[t] = dl;
        __syncthreads();
        if (t < 128)
            Dlp[(size_t)(l * 4 + cq) * 128 + t] = dred[t] + dred[128 + t];
    }
}

// ---------------------------------------------------------------------------
// K3 attn_gemm: 1024 blocks x 256 thr (4 waves: 2 wm x 2 wc). Block =
// (unique u, nh): 128n x 128h half for one distinct (b,label) pair.
// Blocks with u >= nuniq exit immediately (dedup: ~325/512 expected live).
// Counted-vmcnt 2-deep DMA pipeline; pooled partials computed in-block.
// ---------------------------------------------------------------------------
__global__ __launch_bounds__(256, 4) void attn_gemm(
    const float* __restrict__ W_att_f, const float* __restrict__ b_att_f,
    const float* __restrict__ b_att_h, const float* __restrict__ Dlp,
    const int*   __restrict__ uled,    const int* __restrict__ nuniq,
    const u16*   __restrict__ WgT,     const u16* __restrict__ fT,
    u16* __restrict__ pPb, float* __restrict__ pA) {

    __shared__ __align__(16) char Ash[2][8192];    // 128n x 32c bf16, swizzled
    __shared__ __align__(16) char Bsh[2][8192];    // 128h x 32c bf16, swizzled
    __shared__ float d_s[HATT_];
    __shared__ float wf_s[HATT_];
    __shared__ float attn_part[2][128];
    __shared__ float attn_s[128];

    const int t = threadIdx.x;
    const int idx = blockIdx.x;
    const int u = idx >> 1, nh = idx & 1;
    if (u >= nuniq[0]) return;
    const int ul = uled[u];
    const int bq = ul & 0xffff, l = ul >> 16;
    const int b = bq >> 6;

    if (t < HATT_) {
        d_s[t] = b_att_h[t]
               + Dlp[(size_t)(l * 4 + 0) * 128 + t]
               + Dlp[(size_t)(l * 4 + 1) * 128 + t]
               + Dlp[(size_t)(l * 4 + 2) * 128 + t]
               + Dlp[(size_t)(l * 4 + 3) * 128 + t];
        wf_s[t] = W_att_f[t];
    }

    const u16* fTb = fT + (size_t)b * HW_ * C_ + (size_t)nh * 128 * C_;
    const u16* Wl  = WgT + (size_t)l * 65536;      // elements

    const int an0  = t >> 2;                       // n row; it adds 64
    const int asl0 = (t & 3) ^ ((an0 >> 1) & 3);   // inverse swizzle on source

    #define STAGE(s_) {                                                       \
        _Pragma("unroll")                                                     \
        for (int it = 0; it < 2; ++it)                                        \
            gl2lds16(fTb + (size_t)(it * 64 + an0) * C_ + (s_) * 32           \
                         + asl0 * 8,                                          \
                     &Ash[(s_) & 1][(it * 256 + t) * 16]);                    \
        _Pragma("unroll")                                                     \
        for (int it = 0; it < 2; ++it)                                        \
            gl2lds16(Wl + (size_t)(s_) * 4096 + (size_t)(it * 256 + t) * 8,   \
                     &Bsh[(s_) & 1][(it * 256 + t) * 16]);                    \
    }

    const int lane = t & 63, w = t >> 6;
    const int wm = w >> 1, wc = w & 1;             // 2 n-halves x 2 h-halves
    const int lr = lane & 15, lk = lane >> 4;

    const f32x4 zero = {0.f, 0.f, 0.f, 0.f};
    f32x4 acc[4][4];
    #pragma unroll
    for (int mi = 0; mi < 4; ++mi)
        #pragma unroll
        for (int ni = 0; ni < 4; ++ni) acc[mi][ni] = zero;

    STAGE(0);
    STAGE(1);
    asm volatile("s_waitcnt vmcnt(4)" ::: "memory");   // tile 0 landed
    __builtin_amdgcn_sched_barrier(0);
    __builtin_amdgcn_s_barrier();

    #pragma unroll
    for (int s = 0; s < 16; ++s) {
        const char* Ab = Ash[s & 1];
        const char* Bb = Bsh[s & 1];
        short8 af[4], bf[4];
        #pragma unroll
        for (int mi = 0; mi < 4; ++mi) {
            const int nl = wm * 64 + mi * 16 + lr;
            af[mi] = *(const short8*)(Ab + nl * 64 + ((lk ^ ((nl >> 1) & 3)) * 16));
        }
        #pragma unroll
        for (int ni = 0; ni < 4; ++ni) {
            const int h = wc * 64 + ni * 16 + lr;
            bf[ni] = *(const short8*)(Bb + h * 64 + ((lk ^ ((h >> 1) & 3)) * 16));
        }
        asm volatile("s_waitcnt lgkmcnt(0)" ::: "memory");
        __builtin_amdgcn_sched_barrier(0);
        __builtin_amdgcn_s_barrier();              // all waves done reading buf
        if (s < 14) STAGE(s + 2);                  // overwrite just-read buf
        #pragma unroll
        for (int mi = 0; mi < 4; ++mi)
            #pragma unroll
            for (int ni = 0; ni < 4; ++ni)
                acc[mi][ni] = __builtin_amdgcn_mfma_f32_16x16x32_bf16(
                    af[mi], bf[ni], acc[mi][ni], 0, 0, 0);
        if (s < 15) {
            __builtin_amdgcn_sched_barrier(0);     // keep MFMAs above the wait
            if (s < 14) asm volatile("s_waitcnt vmcnt(4)" ::: "memory");
            else        asm volatile("s_waitcnt vmcnt(0)" ::: "memory");
            __builtin_amdgcn_sched_barrier(0);
            __builtin_amdgcn_s_barrier();          // tile s+1 visible to all
        }
    }

    // ---- epilogue: gelu(hidden + D) . wf   (C/D: col(h)=lr, row(n)=lk*4+j)
    #pragma unroll
    for (int mi = 0; mi < 4; ++mi) {
        #pragma unroll
        for (int j = 0; j < 4; ++j) {
            float sum = 0.f;
            #pragma unroll
            for (int ni = 0; ni < 4; ++ni) {
                const int h = wc * 64 + ni * 16 + lr;
                sum += gelu_fast(acc[mi][ni][j] + d_s[h]) * wf_s[h];
            }
            sum += __shfl_xor(sum, 1);
            sum += __shfl_xor(sum, 2);
            sum += __shfl_xor(sum, 4);
            sum += __shfl_xor(sum, 8);
            if (lr == 0) attn_part[wc][wm * 64 + mi * 16 + lk * 4 + j] = sum;
        }
    }
    __syncthreads();
    if (t < 128)
        attn_s[t] = sigmoid_(attn_part[0][t] + attn_part[1][t] + b_att_f[0]);
    __syncthreads();
    if (t < 64) {
        float a = attn_s[t] + attn_s[t + 64];
        #pragma unroll
        for (int m = 1; m < 64; m <<= 1) a += __shfl_xor(a, m);
        if (t == 0) pA[u * 2 + nh] = a;
    }

    // ---- pooled partial: p[c] = sum_{n in half} attn[n] fT[n][c]
    float* pred = (float*)Ash;                     // [2][512] f32, Ash dead
    {
        const int ng = t >> 7, cb = (t & 127) * 4;
        const u16* fp = fTb + cb;
        f32x4 p = zero;
        #pragma unroll 8
        for (int n = ng * 64; n < ng * 64 + 64; ++n) {
            const uint2 v = *(const uint2*)(fp + (size_t)n * C_);
            const float a = attn_s[n];
            p.x += a * __uint_as_float(v.x << 16);
            p.y += a * __uint_as_float(v.x & 0xffff0000u);
            p.z += a * __uint_as_float(v.y << 16);
            p.w += a * __uint_as_float(v.y & 0xffff0000u);
        }
        *(f32x4*)&pred[ng * 512 + cb] = p;
    }
    __syncthreads();
    {   // combine 2 n-groups, pack to bf16: thread t owns c = 2t, 2t+1
        const int c0 = t * 2;
        const float v0 = pred[c0]     + pred[512 + c0];
        const float v1 = pred[c0 + 1] + pred[512 + c0 + 1];
        u16 pk[2] = {f2bf(v0), f2bf(v1)};
        *(u32*)&pPb[(size_t)(u * 2 + nh) * 512 + c0] = *(u32*)pk;
    }
}

// ---------------------------------------------------------------------------
// K4 mlp_head: 256 blocks x 512 thr, 2 unique u per block; scatter logits
// to every bq in each unique's sorted run.
// ---------------------------------------------------------------------------
__global__ __launch_bounds__(512) void mlp_head(
    const int*   __restrict__ uled,  const int* __restrict__ ustart,
    const int*   __restrict__ nuniq, const int* __restrict__ sperm,
    const float* __restrict__ Gl, const float* __restrict__ Bl,
    const float* __restrict__ b_mlp1, const float* __restrict__ W_mlp2,
    const float* __restrict__ b_mlp2, const u16* __restrict__ pPb,
    const float* __restrict__ pA,     const u16* __restrict__ W1bf,
    float* __restrict__ out) {

    __shared__ float pooled_s[2][C_];
    __shared__ float zred[2][2][HMLP_];
    __shared__ float z_s[2][HMLP_];
    __shared__ float red_s[32 * NCLS_];

    const int t = threadIdx.x;
    const int u0 = blockIdx.x * 2;
    const int nu = nuniq[0];
    if (u0 >= nu) return;                          // whole block idle

    {
        const int ui = t >> 8, cc = (t & 255) * 2;
        const int u = u0 + ui;
        if (u < nu) {
            const int l = uled[u] >> 16;
            const float A = pA[u * 2] + pA[u * 2 + 1];
            const float inv = 1.0f / (A + 1e-8f);
            #pragma unroll
            for (int i = 0; i < 2; ++i) {
                const int c = cc + i;
                const float p = bf2f(pPb[(size_t)(u * 2) * 512 + c])
                              + bf2f(pPb[(size_t)(u * 2 + 1) * 512 + c]);
                pooled_s[ui][c] = (Gl[l * C_ + c] * p + Bl[l * C_ + c] * A) * inv;
            }
        } else {
            pooled_s[ui][cc] = 0.f;
            pooled_s[ui][cc + 1] = 0.f;
        }
    }
    __syncthreads();

    {
        const int hp = t & 255, cg = t >> 8;
        float z00 = 0.f, z01 = 0.f, z10 = 0.f, z11 = 0.f;
        const u16* wp = W1bf + hp * 2;
        #pragma unroll 8
        for (int c = cg * 256; c < cg * 256 + 256; ++c) {
            const u32 v = *(const u32*)(wp + (size_t)c * HMLP_);
            const float w0 = __uint_as_float(v << 16);
            const float w1 = __uint_as_float(v & 0xffff0000u);
            const float pa = pooled_s[0][c], pb = pooled_s[1][c];
            z00 += pa * w0; z01 += pa * w1;
            z10 += pb * w0; z11 += pb * w1;
        }
        float2 a0 = {z00, z01}, a1 = {z10, z11};
        *(float2*)&zred[cg][0][hp * 2] = a0;
        *(float2*)&zred[cg][1][hp * 2] = a1;
    }
    __syncthreads();
    {
        const int ui = t >> 8, h2 = (t & 255) * 2;
        #pragma unroll
        for (int i = 0; i < 2; ++i) {
            const int h = h2 + i;
            z_s[ui][h] = gelu_fast(zred[0][ui][h] + zred[1][ui][h] + b_mlp1[h]);
        }
    }
    __syncthreads();

    #pragma unroll
    for (int ui = 0; ui < 2; ++ui) {
        const int u = u0 + ui;
        if (t < 448) {
            const int o = t % 14, seg = t / 14;
            float s = 0.f;
            #pragma unroll
            for (int k = 0; k < 16; ++k) {
                const int h = seg * 16 + k;
                s += z_s[ui][h] * W_mlp2[h * NCLS_ + o];
            }
            red_s[seg * NCLS_ + o] = s;
        }
        __syncthreads();
        if (u < nu && t < NCLS_) {
            float s = b_mlp2[t];
            #pragma unroll
            for (int seg = 0; seg < 32; ++seg) s += red_s[seg * NCLS_ + t];
            const int r0 = ustart[u], r1 = ustart[u + 1];
            for (int r = r0; r < r1; ++r)
                out[sperm[r] * NCLS_ + t] = s;      // scatter to all dupes
        }
        __syncthreads();
    }
}

// ---------------------------------------------------------------------------
extern "C" void kernel_launch(void* const* d_in, const int* in_sizes, int n_in,
                              void* d_out, int out_size, void* d_ws, size_t ws_size,
                              hipStream_t stream) {
    const float* feature   = (const float*)d_in[0];
    const int*   label_ids = (const int*)  d_in[1];
    const float* qt        = (const float*)d_in[2];
    const float* W_film    = (const float*)d_in[3];
    const float* b_film    = (const float*)d_in[4];
    const float* W_att_h   = (const float*)d_in[5];
    const float* b_att_h   = (const float*)d_in[6];
    const float* W_att_f   = (const float*)d_in[7];
    const float* b_att_f   = (const float*)d_in[8];
    const float* W_mlp1    = (const float*)d_in[9];
    const float* b_mlp1    = (const float*)d_in[10];
    const float* W_mlp2    = (const float*)d_in[11];
    const float* b_mlp2    = (const float*)d_in[12];
    float* out = (float*)d_out;

    char* wsb    = (char*)d_ws;
    float* GBp   = (float*)wsb;                  // 1 MB (K1 -> K2)
    u16*   pPb   = (u16*)  wsb;                  // 1 MB (K3 -> K4, aliases GBp)
    float* pA    = (float*)(wsb + 1048576);      // 4 KB
    int*   sperm = (int*)  (wsb + 1052672);      // 2 KB
    int*   uled  = (int*)  (wsb + 1054720);      // 2 KB
    int*   ustart= (int*)  (wsb + 1056768);      // 4 KB
    int*   nuniq = (int*)  (wsb + 1060864);      // 4 KB
    float* Dlp   = (float*)(wsb + 1064960);      // 128 KB
    float* Gl    = (float*)(wsb + 1196032);      // 128 KB
    float* Bl    = (float*)(wsb + 1327104);      // 128 KB
    u16*   W1bf  = (u16*)  (wsb + 1458176);      // 512 KB
    u16*   fTp   = (u16*)  (wsb + 1982464);      // 2 MB
    u16*   WgT   = (u16*)  (wsb + 4079616);      // 8 MB

    hipLaunchKernelGGL(prep_gbp, dim3(256), dim3(256), 0, stream,
                       qt, W_film, GBp);
    hipLaunchKernelGGL(prep_rest, dim3(577), dim3(256), 0, stream,
                       feature, W_mlp1, label_ids, b_film, W_att_h, GBp,
                       W1bf, fTp, sperm, uled, ustart, nuniq, Gl, Bl, WgT, Dlp);
    hipLaunchKernelGGL(attn_gemm, dim3(1024), dim3(256), 0, stream,
                       W_att_f, b_att_f, b_att_h, Dlp, uled, nuniq,
                       WgT, fTp, pPb, pA);
    hipLaunchKernelGGL(mlp_head, dim3(256), dim3(512), 0, stream,
                       uled, ustart, nuniq, sperm, Gl, Bl,
                       b_mlp1, W_mlp2, b_mlp2, pPb, pA, W1bf, out);
}

// Round 14
// 64.036 us; speedup vs baseline: 1.5924x; 1.5924x over previous
//
#include <hip/hip_runtime.h>
#include <hip/hip_bf16.h>

#define B_    8
#define Q_    64
#define C_    512
#define HW_   256
#define E_    512
#define HATT_ 128
#define HMLP_ 512
#define NCLS_ 14
#define NLAB_ 64

typedef unsigned short u16;
typedef unsigned int   u32;
typedef __attribute__((ext_vector_type(8))) short short8;   // 8 bf16
typedef __attribute__((ext_vector_type(4))) float f32x4;

// ws layout (bytes) — total 12,468,224 < 12,582,912 (proven available R2):
//   GBp   @ 0       : 256x1024 f32 (l,cq)-partials of [gamma|beta]  1 MB
//                     (aliased by pPb [512u][2nh][512c] bf16 after prep)
//   pA    @ 1048576 : 512x2 f32 attn-mass partials (per unique)      4 KB
//   sperm @ 1052672 : 512 int  bq sorted by key=(b*64+l)             2 KB
//   uled  @ 1054720 : 512 int  per-unique: rep bq | (l<<16)          2 KB
//   ustart@ 1056768 : 513 int  run starts into sperm                 4 KB
//   nuniq @ 1060864 : 1 int                                          4 KB
//   Dlp   @ 1064960 : 256x128 f32 (l,cq)-partials of beta@W_att_h  128 KB
//   Gl    @ 1196032 : 64x512 f32 gamma per label                   128 KB
//   Bl    @ 1327104 : 64x512 f32 beta per label                    128 KB
//   W1bf  @ 1458176 : 512x512 bf16 W_mlp1                          512 KB
//   fT    @ 1982464 : 8x256x512 bf16 feature^T [b][n][c]             2 MB
//   WgT   @ 4079616 : 64 x [16ss][128h][4slot] bf16x8 gamma-scaled,  8 MB
//                     pre-swizzled (slot = g' ^ ((h>>1)&3)) so linear
//                     DMA into LDS yields the conflict-free tile.

__device__ __forceinline__ float gelu_fast(float x) {
    const float ax = fabsf(x);
    const float t  = __builtin_amdgcn_rcpf(1.0f + 0.3275911f * ax);
    const float p  = t * (0.254829592f +
                     t * (-0.284496736f +
                     t * (1.421413741f +
                     t * (-1.453152027f +
                     t * 1.061405429f))));
    const float e  = __expf(-x * x);
    const float er = copysignf(1.0f - p * e, x);
    return 0.5f * x * (1.0f + er);
}
__device__ __forceinline__ float sigmoid_(float x) {
    return 1.0f / (1.0f + __expf(-x));
}
__device__ __forceinline__ u16 f2bf(float x) {              // RNE f32->bf16
    u32 u = __float_as_uint(x);
    u32 r = (u + 0x7fffu + ((u >> 16) & 1u)) >> 16;
    return (u16)r;
}
__device__ __forceinline__ float bf2f(u16 u) {
    return __uint_as_float(((u32)u) << 16);
}
// async global->LDS DMA, 16B/lane; LDS dest = wave-uniform base + lane*16
__device__ __forceinline__ void gl2lds16(const void* gsrc, void* ldsdst) {
    __builtin_amdgcn_global_load_lds(
        (const __attribute__((address_space(1))) u32*)gsrc,
        (__attribute__((address_space(3))) u32*)ldsdst, 16, 0, 0);
}

// ---------------------------------------------------------------------------
// K1 prep_gbp: 256 blocks (l,cq) x 256 thr.  GBp partials of qt @ W_film.
// ---------------------------------------------------------------------------
__global__ __launch_bounds__(256) void prep_gbp(
    const float* __restrict__ qt, const float* __restrict__ W_film,
    float* __restrict__ GBp) {
    __shared__ float qrow[128];
    const int bid = blockIdx.x, t = threadIdx.x;
    const int l = bid >> 2, cq = bid & 3;
    if (t < 128) qrow[t] = qt[l * E_ + cq * 128 + t];
    __syncthreads();
    const float* wp = W_film + (size_t)(cq * 128) * 1024 + t * 4;
    f32x4 a = {0.f, 0.f, 0.f, 0.f};
    #pragma unroll 8
    for (int c = 0; c < 128; ++c) {
        const float4 w = *(const float4*)(wp + (size_t)c * 1024);
        const float q = qrow[c];
        a.x += q * w.x; a.y += q * w.y; a.z += q * w.z; a.w += q * w.w;
    }
    *(f32x4*)&GBp[(size_t)bid * 1024 + t * 4] = a;
}

// ---------------------------------------------------------------------------
// K2 prep_rest: 577 blocks x 256 thr.
//  [0,256)   fT[b][n][c] = bf16(feature[b][c][n])
//  [256,320) W1bf = bf16(W_mlp1)
//  320       PARALLEL sort by key=(b*64+l) + unique-run detection
//            (two 512-wide Hillis-Steele scans; no thread-0 serial loops)
//  [321,577) (l,cq): Gl/Bl (inline GBp reduce); WgT pre-scaled+pre-swizzled;
//            Dlp partials (non-atomic)
// ---------------------------------------------------------------------------
__global__ __launch_bounds__(256) void prep_rest(
    const float* __restrict__ feature, const float* __restrict__ W_mlp1,
    const int* __restrict__ label_ids, const float* __restrict__ b_film,
    const float* __restrict__ W_att_h, const float* __restrict__ GBp,
    u16* __restrict__ W1bf, u16* __restrict__ fT,
    int* __restrict__ sperm, int* __restrict__ uled,
    int* __restrict__ ustart, int* __restrict__ nuniq,
    float* __restrict__ Gl, float* __restrict__ Bl,
    u16* __restrict__ WgT, float* __restrict__ Dlp) {

    __shared__ __align__(16) char sm[16896];
    const int bid = blockIdx.x, t = threadIdx.x;

    if (bid < 256) {                       // ---- fT transpose
        float (*tile)[65] = (float(*)[65])sm;
        const int b = bid >> 5, c0 = ((bid >> 2) & 7) * 64, n0 = (bid & 3) * 64;
        const float* fb = feature + (size_t)b * C_ * HW_;
        const int cl = t >> 2, nq = t & 3;
        #pragma unroll
        for (int i = 0; i < 4; ++i) {
            float4 v = *(const float4*)&fb[(c0 + cl) * HW_ + n0 + nq * 16 + i * 4];
            tile[cl][nq * 16 + i * 4 + 0] = v.x;
            tile[cl][nq * 16 + i * 4 + 1] = v.y;
            tile[cl][nq * 16 + i * 4 + 2] = v.z;
            tile[cl][nq * 16 + i * 4 + 3] = v.w;
        }
        __syncthreads();
        const int nl = t >> 2, cqq = t & 3;
        u16 pk[16];
        #pragma unroll
        for (int k = 0; k < 16; ++k) pk[k] = f2bf(tile[cqq * 16 + k][nl]);
        u16* dst = fT + (size_t)(b * HW_ + n0 + nl) * C_ + c0 + cqq * 16;
        *(uint4*)dst       = *(uint4*)pk;
        *(uint4*)(dst + 8) = *(uint4*)(pk + 8);
    } else if (bid < 320) {                // ---- W1 -> bf16
        const int b2 = bid - 256;
        #pragma unroll
        for (int k = 0; k < 2; ++k) {
            const int idx = (b2 * 512 + k * 256 + t) * 8;
            float4 v0 = *(const float4*)&W_mlp1[idx];
            float4 v1 = *(const float4*)&W_mlp1[idx + 4];
            u16 pk[8] = {f2bf(v0.x), f2bf(v0.y), f2bf(v0.z), f2bf(v0.w),
                         f2bf(v1.x), f2bf(v1.y), f2bf(v1.z), f2bf(v1.w)};
            *(uint4*)&W1bf[idx] = *(uint4*)pk;
        }
    } else if (bid == 320) {               // ---- parallel sort + unique runs
        int* cnt = (int*)sm;               // 512
        int* off = cnt + 512;              // 512
        int* aux = off + 512;              // 512  (6 KB total)
        cnt[t] = 0; cnt[t + 256] = 0;
        __syncthreads();
        const int bqa = t, bqb = t + 256;
        const int ka = (bqa >> 6) * 64 + label_ids[bqa];
        const int kb = (bqb >> 6) * 64 + label_ids[bqb];
        atomicAdd(&cnt[ka], 1);
        atomicAdd(&cnt[kb], 1);
        __syncthreads();
        // inclusive scan of cnt -> off (Hillis-Steele, 2 elems/thread)
        off[t] = cnt[t]; off[t + 256] = cnt[t + 256];
        __syncthreads();
        for (int d = 1; d < 512; d <<= 1) {
            const int i1 = t + 256;
            const int v0 = off[t]  + ((t  >= d) ? off[t  - d] : 0);
            const int v1 = off[i1] + ((i1 >= d) ? off[i1 - d] : 0);
            __syncthreads();
            off[t] = v0; off[i1] = v1;
            __syncthreads();
        }
        // scatter via atomic cursors at exclusive offsets
        aux[t]       = off[t]       - cnt[t];
        aux[t + 256] = off[t + 256] - cnt[t + 256];
        __syncthreads();
        const int pa = atomicAdd(&aux[ka], 1); sperm[pa] = bqa;
        const int pb = atomicAdd(&aux[kb], 1); sperm[pb] = bqb;
        __syncthreads();
        // inclusive scan of non-empty flags -> aux (unique indices)
        aux[t]       = cnt[t]       ? 1 : 0;
        aux[t + 256] = cnt[t + 256] ? 1 : 0;
        __syncthreads();
        for (int d = 1; d < 512; d <<= 1) {
            const int i1 = t + 256;
            const int v0 = aux[t]  + ((t  >= d) ? aux[t  - d] : 0);
            const int v1 = aux[i1] + ((i1 >= d) ? aux[i1 - d] : 0);
            __syncthreads();
            aux[t] = v0; aux[i1] = v1;
            __syncthreads();
        }
        const int nu = aux[511];
        #pragma unroll
        for (int e = 0; e < 2; ++e) {
            const int k = t + e * 256;
            if (cnt[k]) {
                const int uidx = aux[k] - 1;
                const int st = off[k] - cnt[k];
                ustart[uidx] = st;
                uled[uidx]   = sperm[st] | ((k & 63) << 16);
            }
        }
        if (t == 0) nuniq[0] = nu;
        for (int j = t; j <= 512; j += 256)
            if (j >= nu) ustart[j] = 512;
    } else {                               // ---- Gl/Bl + WgT + Dlp
        float* g_s  = (float*)sm;          // 128
        float* b_s  = g_s + 128;           // 128
        float* dred = b_s + 128;           // 256
        const int wb = bid - 321;
        const int l = wb >> 2, cq = wb & 3;

        if (t < 128) {
            const int c = cq * 128 + t;
            float g = b_film[c], be = b_film[512 + c];
            #pragma unroll
            for (int j = 0; j < 4; ++j) {
                g  += GBp[(size_t)(l * 4 + j) * 1024 + c];
                be += GBp[(size_t)(l * 4 + j) * 1024 + 512 + c];
            }
            g_s[t] = g; b_s[t] = be;
            Gl[l * C_ + c] = g;
            Bl[l * C_ + c] = be;
        }
        __syncthreads();

        const int h = t & 127, ch = t >> 7;
        const int hswz = (h >> 1) & 3;
        float dl = 0.f;
        #pragma unroll
        for (int sl = 0; sl < 2; ++sl) {
            const int ss = cq * 4 + ch * 2 + sl;    // superstep in [0,16)
            char* dst = (char*)WgT + (size_t)l * 131072 + ss * 8192 + h * 64;
            #pragma unroll
            for (int g = 0; g < 4; ++g) {
                u16 pk[8];
                #pragma unroll
                for (int j = 0; j < 8; ++j) {
                    const int cl = ch * 64 + sl * 32 + g * 8 + j;
                    const float w = W_att_h[(size_t)(cq * 128 + cl) * HATT_ + h];
                    pk[j] = f2bf(g_s[cl] * w);
                    dl += b_s[cl] * w;
                }
                *(uint4*)(dst + ((g ^ hswz) * 16)) = *(uint4*)pk;
            }
        }
        dred[t] = dl;
        __syncthreads();
        if (t < 128)
            Dlp[(size_t)(l * 4 + cq) * 128 + t] = dred[t] + dred[128 + t];
    }
}

// ---------------------------------------------------------------------------
// K3 attn_gemm: 1024 blocks x 256 thr (4 waves: 2 wm x 2 wc). Block =
// (unique u, nh): 128n x 128h half for one distinct (b,label) pair.
// Blocks with u >= nuniq exit immediately (dedup: ~325/512 expected live).
// Counted-vmcnt 2-deep DMA pipeline; pooled partials computed in-block.
// ---------------------------------------------------------------------------
__global__ __launch_bounds__(256, 4) void attn_gemm(
    const float* __restrict__ W_att_f, const float* __restrict__ b_att_f,
    const float* __restrict__ b_att_h, const float* __restrict__ Dlp,
    const int*   __restrict__ uled,    const int* __restrict__ nuniq,
    const u16*   __restrict__ WgT,     const u16* __restrict__ fT,
    u16* __restrict__ pPb, float* __restrict__ pA) {

    __shared__ __align__(16) char Ash[2][8192];    // 128n x 32c bf16, swizzled
    __shared__ __align__(16) char Bsh[2][8192];    // 128h x 32c bf16, swizzled
    __shared__ float d_s[HATT_];
    __shared__ float wf_s[HATT_];
    __shared__ float attn_part[2][128];
    __shared__ float attn_s[128];

    const int t = threadIdx.x;
    const int idx = blockIdx.x;
    const int u = idx >> 1, nh = idx & 1;
    if (u >= nuniq[0]) return;
    const int ul = uled[u];
    const int bq = ul & 0xffff, l = ul >> 16;
    const int b = bq >> 6;

    if (t < HATT_) {
        d_s[t] = b_att_h[t]
               + Dlp[(size_t)(l * 4 + 0) * 128 + t]
               + Dlp[(size_t)(l * 4 + 1) * 128 + t]
               + Dlp[(size_t)(l * 4 + 2) * 128 + t]
               + Dlp[(size_t)(l * 4 + 3) * 128 + t];
        wf_s[t] = W_att_f[t];
    }

    const u16* fTb = fT + (size_t)b * HW_ * C_ + (size_t)nh * 128 * C_;
    const u16* Wl  = WgT + (size_t)l * 65536;      // elements

    const int an0  = t >> 2;                       // n row; it adds 64
    const int asl0 = (t & 3) ^ ((an0 >> 1) & 3);   // inverse swizzle on source

    #define STAGE(s_) {                                                       \
        _Pragma("unroll")                                                     \
        for (int it = 0; it < 2; ++it)                                        \
            gl2lds16(fTb + (size_t)(it * 64 + an0) * C_ + (s_) * 32           \
                         + asl0 * 8,                                          \
                     &Ash[(s_) & 1][(it * 256 + t) * 16]);                    \
        _Pragma("unroll")                                                     \
        for (int it = 0; it < 2; ++it)                                        \
            gl2lds16(Wl + (size_t)(s_) * 4096 + (size_t)(it * 256 + t) * 8,   \
                     &Bsh[(s_) & 1][(it * 256 + t) * 16]);                    \
    }

    const int lane = t & 63, w = t >> 6;
    const int wm = w >> 1, wc = w & 1;             // 2 n-halves x 2 h-halves
    const int lr = lane & 15, lk = lane >> 4;

    const f32x4 zero = {0.f, 0.f, 0.f, 0.f};
    f32x4 acc[4][4];
    #pragma unroll
    for (int mi = 0; mi < 4; ++mi)
        #pragma unroll
        for (int ni = 0; ni < 4; ++ni) acc[mi][ni] = zero;

    STAGE(0);
    STAGE(1);
    asm volatile("s_waitcnt vmcnt(4)" ::: "memory");   // tile 0 landed
    __builtin_amdgcn_sched_barrier(0);
    __builtin_amdgcn_s_barrier();

    #pragma unroll
    for (int s = 0; s < 16; ++s) {
        const char* Ab = Ash[s & 1];
        const char* Bb = Bsh[s & 1];
        short8 af[4], bf[4];
        #pragma unroll
        for (int mi = 0; mi < 4; ++mi) {
            const int nl = wm * 64 + mi * 16 + lr;
            af[mi] = *(const short8*)(Ab + nl * 64 + ((lk ^ ((nl >> 1) & 3)) * 16));
        }
        #pragma unroll
        for (int ni = 0; ni < 4; ++ni) {
            const int h = wc * 64 + ni * 16 + lr;
            bf[ni] = *(const short8*)(Bb + h * 64 + ((lk ^ ((h >> 1) & 3)) * 16));
        }
        asm volatile("s_waitcnt lgkmcnt(0)" ::: "memory");
        __builtin_amdgcn_sched_barrier(0);
        __builtin_amdgcn_s_barrier();              // all waves done reading buf
        if (s < 14) STAGE(s + 2);                  // overwrite just-read buf
        #pragma unroll
        for (int mi = 0; mi < 4; ++mi)
            #pragma unroll
            for (int ni = 0; ni < 4; ++ni)
                acc[mi][ni] = __builtin_amdgcn_mfma_f32_16x16x32_bf16(
                    af[mi], bf[ni], acc[mi][ni], 0, 0, 0);
        if (s < 15) {
            __builtin_amdgcn_sched_barrier(0);     // keep MFMAs above the wait
            if (s < 14) asm volatile("s_waitcnt vmcnt(4)" ::: "memory");
            else        asm volatile("s_waitcnt vmcnt(0)" ::: "memory");
            __builtin_amdgcn_sched_barrier(0);
            __builtin_amdgcn_s_barrier();          // tile s+1 visible to all
        }
    }

    // ---- epilogue: gelu(hidden + D) . wf   (C/D: col(h)=lr, row(n)=lk*4+j)
    #pragma unroll
    for (int mi = 0; mi < 4; ++mi) {
        #pragma unroll
        for (int j = 0; j < 4; ++j) {
            float sum = 0.f;
            #pragma unroll
            for (int ni = 0; ni < 4; ++ni) {
                const int h = wc * 64 + ni * 16 + lr;
                sum += gelu_fast(acc[mi][ni][j] + d_s[h]) * wf_s[h];
            }
            sum += __shfl_xor(sum, 1);
            sum += __shfl_xor(sum, 2);
            sum += __shfl_xor(sum, 4);
            sum += __shfl_xor(sum, 8);
            if (lr == 0) attn_part[wc][wm * 64 + mi * 16 + lk * 4 + j] = sum;
        }
    }
    __syncthreads();
    if (t < 128)
        attn_s[t] = sigmoid_(attn_part[0][t] + attn_part[1][t] + b_att_f[0]);
    __syncthreads();
    if (t < 64) {
        float a = attn_s[t] + attn_s[t + 64];
        #pragma unroll
        for (int m = 1; m < 64; m <<= 1) a += __shfl_xor(a, m);
        if (t == 0) pA[u * 2 + nh] = a;
    }

    // ---- pooled partial: p[c] = sum_{n in half} attn[n] fT[n][c]
    float* pred = (float*)Ash;                     // [2][512] f32, Ash dead
    {
        const int ng = t >> 7, cb = (t & 127) * 4;
        const u16* fp = fTb + cb;
        f32x4 p = zero;
        #pragma unroll 8
        for (int n = ng * 64; n < ng * 64 + 64; ++n) {
            const uint2 v = *(const uint2*)(fp + (size_t)n * C_);
            const float a = attn_s[n];
            p.x += a * __uint_as_float(v.x << 16);
            p.y += a * __uint_as_float(v.x & 0xffff0000u);
            p.z += a * __uint_as_float(v.y << 16);
            p.w += a * __uint_as_float(v.y & 0xffff0000u);
        }
        *(f32x4*)&pred[ng * 512 + cb] = p;
    }
    __syncthreads();
    {   // combine 2 n-groups, pack to bf16: thread t owns c = 2t, 2t+1
        const int c0 = t * 2;
        const float v0 = pred[c0]     + pred[512 + c0];
        const float v1 = pred[c0 + 1] + pred[512 + c0 + 1];
        u16 pk[2] = {f2bf(v0), f2bf(v1)};
        *(u32*)&pPb[(size_t)(u * 2 + nh) * 512 + c0] = *(u32*)pk;
    }
}

// ---------------------------------------------------------------------------
// K4 mlp_head: 256 blocks x 512 thr, 2 unique u per block; scatter logits
// to every bq in each unique's sorted run.
// ---------------------------------------------------------------------------
__global__ __launch_bounds__(512) void mlp_head(
    const int*   __restrict__ uled,  const int* __restrict__ ustart,
    const int*   __restrict__ nuniq, const int* __restrict__ sperm,
    const float* __restrict__ Gl, const float* __restrict__ Bl,
    const float* __restrict__ b_mlp1, const float* __restrict__ W_mlp2,
    const float* __restrict__ b_mlp2, const u16* __restrict__ pPb,
    const float* __restrict__ pA,     const u16* __restrict__ W1bf,
    float* __restrict__ out) {

    __shared__ float pooled_s[2][C_];
    __shared__ float zred[2][2][HMLP_];
    __shared__ float z_s[2][HMLP_];
    __shared__ float red_s[32 * NCLS_];

    const int t = threadIdx.x;
    const int u0 = blockIdx.x * 2;
    const int nu = nuniq[0];
    if (u0 >= nu) return;                          // whole block idle

    {
        const int ui = t >> 8, cc = (t & 255) * 2;
        const int u = u0 + ui;
        if (u < nu) {
            const int l = uled[u] >> 16;
            const float A = pA[u * 2] + pA[u * 2 + 1];
            const float inv = 1.0f / (A + 1e-8f);
            #pragma unroll
            for (int i = 0; i < 2; ++i) {
                const int c = cc + i;
                const float p = bf2f(pPb[(size_t)(u * 2) * 512 + c])
                              + bf2f(pPb[(size_t)(u * 2 + 1) * 512 + c]);
                pooled_s[ui][c] = (Gl[l * C_ + c] * p + Bl[l * C_ + c] * A) * inv;
            }
        } else {
            pooled_s[ui][cc] = 0.f;
            pooled_s[ui][cc + 1] = 0.f;
        }
    }
    __syncthreads();

    {
        const int hp = t & 255, cg = t >> 8;
        float z00 = 0.f, z01 = 0.f, z10 = 0.f, z11 = 0.f;
        const u16* wp = W1bf + hp * 2;
        #pragma unroll 8
        for (int c = cg * 256; c < cg * 256 + 256; ++c) {
            const u32 v = *(const u32*)(wp + (size_t)c * HMLP_);
            const float w0 = __uint_as_float(v << 16);
            const float w1 = __uint_as_float(v & 0xffff0000u);
            const float pa = pooled_s[0][c], pb = pooled_s[1][c];
            z00 += pa * w0; z01 += pa * w1;
            z10 += pb * w0; z11 += pb * w1;
        }
        float2 a0 = {z00, z01}, a1 = {z10, z11};
        *(float2*)&zred[cg][0][hp * 2] = a0;
        *(float2*)&zred[cg][1][hp * 2] = a1;
    }
    __syncthreads();
    {
        const int ui = t >> 8, h2 = (t & 255) * 2;
        #pragma unroll
        for (int i = 0; i < 2; ++i) {
            const int h = h2 + i;
            z_s[ui][h] = gelu_fast(zred[0][ui][h] + zred[1][ui][h] + b_mlp1[h]);
        }
    }
    __syncthreads();

    #pragma unroll
    for (int ui = 0; ui < 2; ++ui) {
        const int u = u0 + ui;
        if (t < 448) {
            const int o = t % 14, seg = t / 14;
            float s = 0.f;
            #pragma unroll
            for (int k = 0; k < 16; ++k) {
                const int h = seg * 16 + k;
                s += z_s[ui][h] * W_mlp2[h * NCLS_ + o];
            }
            red_s[seg * NCLS_ + o] = s;
        }
        __syncthreads();
        if (u < nu && t < NCLS_) {
            float s = b_mlp2[t];
            #pragma unroll
            for (int seg = 0; seg < 32; ++seg) s += red_s[seg * NCLS_ + t];
            const int r0 = ustart[u], r1 = ustart[u + 1];
            for (int r = r0; r < r1; ++r)
                out[sperm[r] * NCLS_ + t] = s;      // scatter to all dupes
        }
        __syncthreads();
    }
}

// ---------------------------------------------------------------------------
extern "C" void kernel_launch(void* const* d_in, const int* in_sizes, int n_in,
                              void* d_out, int out_size, void* d_ws, size_t ws_size,
                              hipStream_t stream) {
    const float* feature   = (const float*)d_in[0];
    const int*   label_ids = (const int*)  d_in[1];
    const float* qt        = (const float*)d_in[2];
    const float* W_film    = (const float*)d_in[3];
    const float* b_film    = (const float*)d_in[4];
    const float* W_att_h   = (const float*)d_in[5];
    const float* b_att_h   = (const float*)d_in[6];
    const float* W_att_f   = (const float*)d_in[7];
    const float* b_att_f   = (const float*)d_in[8];
    const float* W_mlp1    = (const float*)d_in[9];
    const float* b_mlp1    = (const float*)d_in[10];
    const float* W_mlp2    = (const float*)d_in[11];
    const float* b_mlp2    = (const float*)d_in[12];
    float* out = (float*)d_out;

    char* wsb    = (char*)d_ws;
    float* GBp   = (float*)wsb;                  // 1 MB (K1 -> K2)
    u16*   pPb   = (u16*)  wsb;                  // 1 MB (K3 -> K4, aliases GBp)
    float* pA    = (float*)(wsb + 1048576);      // 4 KB
    int*   sperm = (int*)  (wsb + 1052672);      // 2 KB
    int*   uled  = (int*)  (wsb + 1054720);      // 2 KB
    int*   ustart= (int*)  (wsb + 1056768);      // 4 KB
    int*   nuniq = (int*)  (wsb + 1060864);      // 4 KB
    float* Dlp   = (float*)(wsb + 1064960);      // 128 KB
    float* Gl    = (float*)(wsb + 1196032);      // 128 KB
    float* Bl    = (float*)(wsb + 1327104);      // 128 KB
    u16*   W1bf  = (u16*)  (wsb + 1458176);      // 512 KB
    u16*   fTp   = (u16*)  (wsb + 1982464);      // 2 MB
    u16*   WgT   = (u16*)  (wsb + 4079616);      // 8 MB

    hipLaunchKernelGGL(prep_gbp, dim3(256), dim3(256), 0, stream,
                       qt, W_film, GBp);
    hipLaunchKernelGGL(prep_rest, dim3(577), dim3(256), 0, stream,
                       feature, W_mlp1, label_ids, b_film, W_att_h, GBp,
                       W1bf, fTp, sperm, uled, ustart, nuniq, Gl, Bl, WgT, Dlp);
    hipLaunchKernelGGL(attn_gemm, dim3(1024), dim3(256), 0, stream,
                       W_att_f, b_att_f, b_att_h, Dlp, uled, nuniq,
                       WgT, fTp, pPb, pA);
    hipLaunchKernelGGL(mlp_head, dim3(256), dim3(512), 0, stream,
                       uled, ustart, nuniq, sperm, Gl, Bl,
                       b_mlp1, W_mlp2, b_mlp2, pPb, pA, W1bf, out);
}